// Round 5
// baseline (5979.014 us; speedup 1.0000x reference)
//
#include <hip/hip_runtime.h>
#include <hip/hip_cooperative_groups.h>
#include <math.h>

namespace cg = cooperative_groups;

#define VOCABSZ 32000
#define EMBD 512
#define HIDD 512
#define BSZ 32
#define TLEN 32
#define G4 2048
#define LCB 128              // vocab cols per logits block
#define NCB 250              // logits working blocks
#define NB 256               // grid blocks
#define PS 8192              // part array stride (32 rows * 256 slots)

__device__ __forceinline__ float sigmoidf_(float x) { return 1.f / (1.f + expf(-x)); }

// ---------------------------------------------------------------------------
// One cooperative megakernel: 33 LSTM steps, 2 grid syncs per step.
//   CELL   : blocks 0..255, block b owns gate-cols {2b, 2b+1}; thread (r, sl)
//            = (tid>>3, tid&7) accumulates a 128-K slice, shfl-combined.
//   LOGITS : blocks 0..249, 128 vocab cols x 32 rows x K=512; double-buffered
//            LDS GEMM + fused per-block softmax partials -> part SoA.
//   REDUCE : ALL blocks redundantly combine 250 partials -> per-block s_tok
//            (next-step tokens in LDS); block 0 alone accumulates CE.
// ---------------------------------------------------------------------------
__global__ __launch_bounds__(256, 1) void mega_kernel(
    const float* __restrict__ x, const int* __restrict__ labels,
    const void* __restrict__ coin, const float* __restrict__ emb,
    const float* __restrict__ Wi, const float* __restrict__ Wh,
    const float* __restrict__ bias, const float* __restrict__ Wo,
    const float* __restrict__ bo,
    float* __restrict__ hA, float* __restrict__ hB, float* __restrict__ cst,
    float* __restrict__ part, float* __restrict__ out)
{
    cg::grid_group grid = cg::this_grid();
    __shared__ float s_w[2][32][128];    // 32 KB  logits Wo tiles
    __shared__ float s_h[2][32][36];     // 9 KB   logits h tiles [k][r]
    __shared__ float s_out[32][LCB];     // 16 KB  logits block output
    __shared__ int   s_tok[32];
    __shared__ float s_ce[32];
    __shared__ int   s_flag;

    const int tid = threadIdx.x;
    const int blk = blockIdx.x;

    // ---- init ----
    if (tid == 0) {
        // coin dtype probe: uint8 bools pack to words like 0x00010001 (>1)
        const unsigned int* cw = (const unsigned int*)coin;
        int f = 0;
        for (int i = 0; i < 256; ++i) if (cw[i] > 1u) f = 1;
        s_flag = f;
    }
    if (tid < 32) { s_tok[tid] = 1; s_ce[tid] = 0.f; }   // START = 1
    {
        int i = blk * 256 + tid;
        if (i < BSZ * HIDD) { hA[i] = x[i]; cst[i] = 0.f; }
    }
    grid.sync();

    for (int s = 0; s < 33; ++s) {
        const float* hsrc = (s & 1) ? hB : hA;
        float* hdst = (s & 1) ? hA : hB;

        // ================= CELL =================
        {
            int r = tid >> 3, sl = tid & 7;
            const float* xr = emb + (size_t)s_tok[r] * EMBD;
            const float* hr = hsrc + r * HIDD;
            int j = 2 * blk;
            float a0=0,a1=0,a2=0,a3=0,b0=0,b1=0,b2=0,b3=0;
            const float* X; const float* W; int kb;
            if (sl < 4) { X = xr; W = Wi; kb = sl * 128; }
            else        { X = hr; W = Wh; kb = (sl - 4) * 128; }
            #pragma unroll 4
            for (int kk = 0; kk < 128; ++kk) {
                float xv = X[kb + kk];
                const float* wrow = W + (size_t)(kb + kk) * G4;
                float2 wi_ = *(const float2*)&wrow[j];
                float2 wf_ = *(const float2*)&wrow[j + 512];
                float2 wg_ = *(const float2*)&wrow[j + 1024];
                float2 wo_ = *(const float2*)&wrow[j + 1536];
                a0 += xv * wi_.x; b0 += xv * wi_.y;
                a1 += xv * wf_.x; b1 += xv * wf_.y;
                a2 += xv * wg_.x; b2 += xv * wg_.y;
                a3 += xv * wo_.x; b3 += xv * wo_.y;
            }
            #pragma unroll
            for (int d = 1; d < 8; d <<= 1) {
                a0 += __shfl_xor(a0, d); a1 += __shfl_xor(a1, d);
                a2 += __shfl_xor(a2, d); a3 += __shfl_xor(a3, d);
                b0 += __shfl_xor(b0, d); b1 += __shfl_xor(b1, d);
                b2 += __shfl_xor(b2, d); b3 += __shfl_xor(b3, d);
            }
            if (sl == 0) {
                {
                    float i_ = a0 + bias[j], f_ = a1 + bias[j + 512];
                    float g_ = a2 + bias[j + 1024], o_ = a3 + bias[j + 1536];
                    float ci = cst[r * HIDD + j];
                    float cn = sigmoidf_(f_) * ci + sigmoidf_(i_) * tanhf(g_);
                    cst[r * HIDD + j] = cn;
                    hdst[r * HIDD + j] = sigmoidf_(o_) * tanhf(cn);
                }
                {
                    int j1 = j + 1;
                    float i_ = b0 + bias[j1], f_ = b1 + bias[j1 + 512];
                    float g_ = b2 + bias[j1 + 1024], o_ = b3 + bias[j1 + 1536];
                    float ci = cst[r * HIDD + j1];
                    float cn = sigmoidf_(f_) * ci + sigmoidf_(i_) * tanhf(g_);
                    cst[r * HIDD + j1] = cn;
                    hdst[r * HIDD + j1] = sigmoidf_(o_) * tanhf(cn);
                }
            }
        }
        grid.sync();

        // ================= LOGITS =================
        if (blk < NCB) {
            const float* h = hdst;
            int c0 = blk * LCB;
            int c4 = tid & 31;
            int rg = tid >> 5;
            int skk = tid & 31;
            int sr = tid >> 5;

            float acc[4][4];
            #pragma unroll
            for (int a = 0; a < 4; ++a)
                #pragma unroll
                for (int q = 0; q < 4; ++q) acc[a][q] = 0.f;

            // prologue: tile 0
            #pragma unroll
            for (int p = 0; p < 4; ++p) {
                int kk = p * 8 + sr;
                *(float4*)&s_w[0][kk][c4 * 4] =
                    *(const float4*)&Wo[(size_t)kk * VOCABSZ + c0 + c4 * 4];
                s_h[0][skk][p * 8 + sr] = h[(p * 8 + sr) * HIDD + skk];
            }
            __syncthreads();

            float4 wr[4]; float hr2[4];
            for (int tt = 0; tt < 16; ++tt) {
                int cur = tt & 1;
                if (tt < 15) {
                    int kb = (tt + 1) * 32;
                    #pragma unroll
                    for (int p = 0; p < 4; ++p) {
                        int kk = p * 8 + sr;
                        wr[p] = *(const float4*)&Wo[(size_t)(kb + kk) * VOCABSZ + c0 + c4 * 4];
                        hr2[p] = h[(p * 8 + sr) * HIDD + kb + skk];
                    }
                }
                #pragma unroll
                for (int kk = 0; kk < 32; ++kk) {
                    float4 w = *(const float4*)&s_w[cur][kk][c4 * 4];
                    float4 hh = *(const float4*)&s_h[cur][kk][rg * 4];
                    acc[0][0] += hh.x * w.x; acc[0][1] += hh.x * w.y;
                    acc[0][2] += hh.x * w.z; acc[0][3] += hh.x * w.w;
                    acc[1][0] += hh.y * w.x; acc[1][1] += hh.y * w.y;
                    acc[1][2] += hh.y * w.z; acc[1][3] += hh.y * w.w;
                    acc[2][0] += hh.z * w.x; acc[2][1] += hh.z * w.y;
                    acc[2][2] += hh.z * w.z; acc[2][3] += hh.z * w.w;
                    acc[3][0] += hh.w * w.x; acc[3][1] += hh.w * w.y;
                    acc[3][2] += hh.w * w.z; acc[3][3] += hh.w * w.w;
                }
                __syncthreads();
                if (tt < 15) {
                    int nb = cur ^ 1;
                    #pragma unroll
                    for (int p = 0; p < 4; ++p) {
                        int kk = p * 8 + sr;
                        *(float4*)&s_w[nb][kk][c4 * 4] = wr[p];
                        s_h[nb][skk][p * 8 + sr] = hr2[p];
                    }
                }
                __syncthreads();
            }

            float4 bq = *(const float4*)&bo[c0 + c4 * 4];
            #pragma unroll
            for (int a = 0; a < 4; ++a) {
                float4 v;
                v.x = acc[a][0] + bq.x; v.y = acc[a][1] + bq.y;
                v.z = acc[a][2] + bq.z; v.w = acc[a][3] + bq.w;
                *(float4*)&s_out[rg * 4 + a][c4 * 4] = v;
            }
            __syncthreads();

            // per-block softmax partials: 8 slots per row
            int row = tid >> 3, slot = tid & 7;
            int ls = (s < 32) ? s : 0;
            int lab = labels[row * TLEN + ls];
            float m = -INFINITY; int mi = 0;
            for (int cc = slot; cc < LCB; cc += 8) {
                float v = s_out[row][cc];
                int gidx = c0 + cc;
                if (v > m || (v == m && gidx < mi)) { m = v; mi = gidx; }
            }
            #pragma unroll
            for (int d = 1; d < 8; d <<= 1) {
                float om = __shfl_xor(m, d);
                int omi = __shfl_xor(mi, d);
                if (om > m || (om == m && omi < mi)) { m = om; mi = omi; }
            }
            float sm = 0.f;
            for (int cc = slot; cc < LCB; cc += 8) sm += expf(s_out[row][cc] - m);
            #pragma unroll
            for (int d = 1; d < 8; d <<= 1) sm += __shfl_xor(sm, d);

            if (slot == 0) {
                int e = row * 256 + blk;
                part[e] = m;
                part[PS + e] = sm;
                part[2 * PS + e] = __int_as_float(mi);
                int lc = lab - c0;
                part[3 * PS + e] = (lc >= 0 && lc < LCB) ? s_out[row][lc] : -INFINITY;
                int sc = 2 - c0;     // STOP = 2
                part[4 * PS + e] = (sc >= 0 && sc < LCB) ? s_out[row][sc] : -INFINITY;
            }
        }
        grid.sync();

        // ================= REDUCE (redundant in all blocks) =================
        {
            int row = tid >> 3, slot = tid & 7;
            float M = -INFINITY, S = 0.f, av = -INFINITY, lv = -INFINITY, sv = -INFINITY;
            int ai = 0;
            for (int ib = slot; ib < NCB; ib += 8) {
                int e = row * 256 + ib;
                float pm = part[e], ps = part[PS + e];
                int pi = __float_as_int(part[2 * PS + e]);
                float nM = fmaxf(M, pm);
                S = S * expf(M - nM) + ps * expf(pm - nM);
                M = nM;
                if (pm > av || (pm == av && pi < ai)) { av = pm; ai = pi; }
                lv = fmaxf(lv, part[3 * PS + e]);
                sv = fmaxf(sv, part[4 * PS + e]);
            }
            #pragma unroll
            for (int d = 1; d < 8; d <<= 1) {
                float oM = __shfl_xor(M, d), oS = __shfl_xor(S, d);
                float nM = fmaxf(M, oM);
                S = S * expf(M - nM) + oS * expf(oM - nM);
                M = nM;
                float oav = __shfl_xor(av, d); int oai = __shfl_xor(ai, d);
                if (oav > av || (oav == av && oai < ai)) { av = oav; ai = oai; }
                lv = fmaxf(lv, __shfl_xor(lv, d));
                sv = fmaxf(sv, __shfl_xor(sv, d));
            }
            if (slot == 0) {
                float logZ = M + logf(S);
                if (s < 32) {
                    int lab = labels[row * TLEN + s];
                    if (blk == 0) s_ce[row] += logZ - lv;
                    int cn = s_flag ? (int)((const unsigned char*)coin)[row * TLEN + s]
                                    : ((const int*)coin)[row * TLEN + s];
                    s_tok[row] = cn ? ai : lab;
                } else if (blk == 0) {
                    s_ce[row] += logZ - sv;
                }
            }
        }
        __syncthreads();
        if (s == 32 && blk == 0 && tid == 0) {
            float tot = 0.f;
            for (int r2 = 0; r2 < 32; ++r2) tot += s_ce[r2];
            *out = tot / 32.f;
        }
    }
}

// ---------------------------------------------------------------------------
extern "C" void kernel_launch(void* const* d_in, const int* in_sizes, int n_in,
                              void* d_out, int out_size, void* d_ws, size_t ws_size,
                              hipStream_t stream) {
    const float* x      = (const float*)d_in[0];
    const int*   labels = (const int*)  d_in[1];
    const void*  coin   =               d_in[2];
    const float* emb    = (const float*)d_in[3];
    const float* Wi     = (const float*)d_in[4];
    const float* Wh     = (const float*)d_in[5];
    const float* b      = (const float*)d_in[6];
    const float* Wo     = (const float*)d_in[7];
    const float* bo     = (const float*)d_in[8];

    float* ws   = (float*)d_ws;
    float* hA   = ws;                    // 16384
    float* hB   = ws + 16384;            // 16384
    float* cst  = ws + 32768;            // 16384
    float* part = ws + 49152;            // 5 * 8192 = 40960
    float* outp = (float*)d_out;

    void* args[] = {
        (void*)&x, (void*)&labels, (void*)&coin, (void*)&emb,
        (void*)&Wi, (void*)&Wh, (void*)&b, (void*)&Wo, (void*)&bo,
        (void*)&hA, (void*)&hB, (void*)&cst, (void*)&part, (void*)&outp
    };
    hipLaunchCooperativeKernel((void*)mega_kernel, dim3(NB), dim3(256),
                               args, 0, stream);
}

// Round 7
// 5615.366 us; speedup vs baseline: 1.0648x; 1.0648x over previous
//
#include <hip/hip_runtime.h>
#include <hip/hip_cooperative_groups.h>
#include <math.h>

namespace cg = cooperative_groups;

#define VOCABSZ 32000
#define EMBD 512
#define HIDD 512
#define BSZ 32
#define TLEN 32
#define G4 2048
#define LCB 128              // vocab cols per logits block
#define NCB 250              // logits working blocks
#define NB 256               // grid blocks (proven cooperative-validating size)
#define PS 8192              // part array stride (32 rows * 256 slots)

__device__ __forceinline__ float sigmoidf_(float x) { return 1.f / (1.f + expf(-x)); }

// ===========================================================================
// MEGAKERNEL v3: 256 blocks x 512 thr (2 waves/SIMD), 2 grid.syncs per step.
//  CELL  : blk<64; block owns 8 hidden cols (=32 gate cols). X staged in LDS
//          (XOR swizzle, conflict-free), full K=1024 dot per thread (col,2rows),
//          gate exchange via 4KB LDS, cst/hdst updated in place. No pg.
//  LOGITS: blk<250; all of h (64KB) in LDS (broadcast reads), barrier-free
//          K-loop, Wo float4 global->reg; fused per-block softmax partials.
//  REDUCE: all blocks redundantly combine 250 partials -> s_tok; blk0 does CE.
// ===========================================================================
__global__ __launch_bounds__(512, 1) void mega3_kernel(
    const float* __restrict__ x, const int* __restrict__ labels,
    const void* __restrict__ coin, const float* __restrict__ emb,
    const float* __restrict__ Wi, const float* __restrict__ Wh,
    const float* __restrict__ bias, const float* __restrict__ Wo,
    const float* __restrict__ bo,
    float* __restrict__ hA, float* __restrict__ hB, float* __restrict__ cst,
    float* __restrict__ part, float* __restrict__ out)
{
    cg::grid_group grid = cg::this_grid();
    __shared__ __align__(16) float smem[16384];   // 64 KB: X-stage / h-stage / s_out
    __shared__ float sg[1024];                    // 4 KB gate-exchange
    __shared__ int   s_tok[32];
    __shared__ float s_ce[32];
    __shared__ int   s_flag;

    const int tid = threadIdx.x;
    const int blk = blockIdx.x;

    if (tid == 0) {
        // coin dtype probe: uint8 bools pack as 0x00010001-style words (>1)
        const unsigned int* cw = (const unsigned int*)coin;
        int f = 0;
        for (int i = 0; i < 256; ++i) if (cw[i] > 1u) f = 1;
        s_flag = f;
    }
    if (tid < 32) { s_tok[tid] = 1; s_ce[tid] = 0.f; }   // START = 1
    if (blk < 32) {
        int i = blk * 512 + tid;
        hA[i] = x[i];
        cst[i] = 0.f;
    }
    __syncthreads();
    grid.sync();

    for (int s = 0; s < 33; ++s) {
        const float* hsrc = (s & 1) ? hB : hA;
        float* hdst = (s & 1) ? hA : hB;

        // ================= CELL (blk < 64) =================
        if (blk < 64) {
            int cidx = tid & 31;          // gate-col lane: g*8 + jj
            int rowg = tid >> 5;          // 0..15 -> rows 2*rowg, 2*rowg+1
            int g = cidx >> 3;            // gate 0..3 (i,f,g,o)
            int jj = cidx & 7;
            int col = blk * 8 + jj + g * 512;
            float a0 = 0.f, a1 = 0.f;
            #pragma unroll
            for (int half = 0; half < 2; ++half) {
                const float* W = half ? Wh : Wi;
                // stage X[32][512] swizzled: smem[kk*32 + (r ^ (kk&31))]
                #pragma unroll
                for (int it = 0; it < 8; ++it) {
                    int idx4 = it * 512 + tid;       // 0..4095 float4s
                    int r = idx4 >> 7;
                    int kk = (idx4 & 127) << 2;
                    const float* src = half ? &hsrc[r * HIDD + kk]
                                            : &emb[(size_t)s_tok[r] * EMBD + kk];
                    float4 v = *(const float4*)src;
                    smem[((kk + 0) << 5) + (r ^ ((kk + 0) & 31))] = v.x;
                    smem[((kk + 1) << 5) + (r ^ ((kk + 1) & 31))] = v.y;
                    smem[((kk + 2) << 5) + (r ^ ((kk + 2) & 31))] = v.z;
                    smem[((kk + 3) << 5) + (r ^ ((kk + 3) & 31))] = v.w;
                }
                __syncthreads();
                #pragma unroll 8
                for (int kk = 0; kk < 512; ++kk) {
                    float w = W[(size_t)kk * G4 + col];
                    int sw = kk & 31;
                    a0 += smem[(kk << 5) + ((rowg * 2) ^ sw)] * w;
                    a1 += smem[(kk << 5) + ((rowg * 2 + 1) ^ sw)] * w;
                }
                __syncthreads();
            }
            sg[(rowg * 2) * 32 + cidx] = a0;
            sg[(rowg * 2 + 1) * 32 + cidx] = a1;
            __syncthreads();
            if (g == 0) {                 // cidx < 8: gate math for hidden col jh
                int jh = blk * 8 + jj;
                #pragma unroll
                for (int rr = 0; rr < 2; ++rr) {
                    int r = rowg * 2 + rr;
                    float i_ = sg[r * 32 + jj]      + bias[jh];
                    float f_ = sg[r * 32 + jj + 8]  + bias[jh + 512];
                    float g_ = sg[r * 32 + jj + 16] + bias[jh + 1024];
                    float o_ = sg[r * 32 + jj + 24] + bias[jh + 1536];
                    float ci = cst[r * HIDD + jh];
                    float cn = sigmoidf_(f_) * ci + sigmoidf_(i_) * tanhf(g_);
                    cst[r * HIDD + jh] = cn;
                    hdst[r * HIDD + jh] = sigmoidf_(o_) * tanhf(cn);
                }
            }
        }
        grid.sync();

        // ================= LOGITS (blk < 250) =================
        if (blk < NCB) {
            #pragma unroll
            for (int it = 0; it < 8; ++it) {
                int i4 = it * 512 + tid;             // 4096 float4s = 64KB
                *(float4*)&smem[i4 * 4] = *(const float4*)&hdst[i4 * 4];
            }
            __syncthreads();

            int c4 = tid & 31;                       // 4-col group
            int rg = tid >> 5;                       // 0..15 -> 2 rows each
            int c0 = blk * LCB;
            const float* wp = Wo + c0 + (c4 << 2);
            int rb0 = (rg * 2) * HIDD;
            int rb1 = rb0 + HIDD;

            float4 A0 = {0, 0, 0, 0}, A1 = {0, 0, 0, 0};
            #pragma unroll 4
            for (int k = 0; k < 512; k += 4) {
                float4 h0 = *(const float4*)&smem[rb0 + k];
                float4 h1 = *(const float4*)&smem[rb1 + k];
                float4 w0 = *(const float4*)&wp[(size_t)(k + 0) * VOCABSZ];
                float4 w1 = *(const float4*)&wp[(size_t)(k + 1) * VOCABSZ];
                float4 w2 = *(const float4*)&wp[(size_t)(k + 2) * VOCABSZ];
                float4 w3 = *(const float4*)&wp[(size_t)(k + 3) * VOCABSZ];
                A0.x += h0.x * w0.x; A0.y += h0.x * w0.y; A0.z += h0.x * w0.z; A0.w += h0.x * w0.w;
                A1.x += h1.x * w0.x; A1.y += h1.x * w0.y; A1.z += h1.x * w0.z; A1.w += h1.x * w0.w;
                A0.x += h0.y * w1.x; A0.y += h0.y * w1.y; A0.z += h0.y * w1.z; A0.w += h0.y * w1.w;
                A1.x += h1.y * w1.x; A1.y += h1.y * w1.y; A1.z += h1.y * w1.z; A1.w += h1.y * w1.w;
                A0.x += h0.z * w2.x; A0.y += h0.z * w2.y; A0.z += h0.z * w2.z; A0.w += h0.z * w2.w;
                A1.x += h1.z * w2.x; A1.y += h1.z * w2.y; A1.z += h1.z * w2.z; A1.w += h1.z * w2.w;
                A0.x += h0.w * w3.x; A0.y += h0.w * w3.y; A0.z += h0.w * w3.z; A0.w += h0.w * w3.w;
                A1.x += h1.w * w3.x; A1.y += h1.w * w3.y; A1.z += h1.w * w3.z; A1.w += h1.w * w3.w;
            }
            __syncthreads();       // h reads done; smem becomes s_out[32][128]

            float4 bq = *(const float4*)&bo[c0 + (c4 << 2)];
            float* so = smem;
            {
                float4 v;
                v.x = A0.x + bq.x; v.y = A0.y + bq.y; v.z = A0.z + bq.z; v.w = A0.w + bq.w;
                *(float4*)&so[(rg * 2) * LCB + (c4 << 2)] = v;
                v.x = A1.x + bq.x; v.y = A1.y + bq.y; v.z = A1.z + bq.z; v.w = A1.w + bq.w;
                *(float4*)&so[(rg * 2 + 1) * LCB + (c4 << 2)] = v;
            }
            __syncthreads();

            // per-block softmax partials: 16 slots per row
            int row = tid >> 4, slot = tid & 15;
            int ls = (s < 32) ? s : 0;
            int lab = labels[row * TLEN + ls];
            float m = -INFINITY; int mi = 0;
            for (int cc = slot; cc < LCB; cc += 16) {
                float v = so[row * LCB + cc];
                int gidx = c0 + cc;
                if (v > m || (v == m && gidx < mi)) { m = v; mi = gidx; }
            }
            #pragma unroll
            for (int d = 1; d < 16; d <<= 1) {
                float om = __shfl_xor(m, d);
                int omi = __shfl_xor(mi, d);
                if (om > m || (om == m && omi < mi)) { m = om; mi = omi; }
            }
            float sm = 0.f;
            for (int cc = slot; cc < LCB; cc += 16) sm += expf(so[row * LCB + cc] - m);
            #pragma unroll
            for (int d = 1; d < 16; d <<= 1) sm += __shfl_xor(sm, d);

            if (slot == 0) {
                int e = row * 256 + blk;
                part[e] = m;
                part[PS + e] = sm;
                part[2 * PS + e] = __int_as_float(mi);
                int lc = lab - c0;
                part[3 * PS + e] = (lc >= 0 && lc < LCB) ? so[row * LCB + lc] : -INFINITY;
                int sc = 2 - c0;       // STOP = 2
                part[4 * PS + e] = (sc >= 0 && sc < LCB) ? so[row * LCB + sc] : -INFINITY;
            }
        }
        grid.sync();

        // ================= REDUCE (redundant, all blocks) =================
        {
            int row = tid >> 4, slot = tid & 15;
            float M = -INFINITY, S = 0.f, av = -INFINITY, lv = -INFINITY, sv = -INFINITY;
            int ai = 0;
            for (int ib = slot; ib < NCB; ib += 16) {
                int e = row * 256 + ib;
                float pm = part[e], ps = part[PS + e];
                int pi = __float_as_int(part[2 * PS + e]);
                float nM = fmaxf(M, pm);
                S = S * expf(M - nM) + ps * expf(pm - nM);
                M = nM;
                if (pm > av || (pm == av && pi < ai)) { av = pm; ai = pi; }
                lv = fmaxf(lv, part[3 * PS + e]);
                sv = fmaxf(sv, part[4 * PS + e]);
            }
            #pragma unroll
            for (int d = 1; d < 16; d <<= 1) {
                float oM = __shfl_xor(M, d), oS = __shfl_xor(S, d);
                float nM = fmaxf(M, oM);
                S = S * expf(M - nM) + oS * expf(oM - nM);
                M = nM;
                float oav = __shfl_xor(av, d); int oai = __shfl_xor(ai, d);
                if (oav > av || (oav == av && oai < ai)) { av = oav; ai = oai; }
                lv = fmaxf(lv, __shfl_xor(lv, d));
                sv = fmaxf(sv, __shfl_xor(sv, d));
            }
            if (slot == 0) {
                float logZ = M + logf(S);
                if (s < 32) {
                    int lab = labels[row * TLEN + s];
                    if (blk == 0) s_ce[row] += logZ - lv;
                    int cn = s_flag ? (int)((const unsigned char*)coin)[row * TLEN + s]
                                    : ((const int*)coin)[row * TLEN + s];
                    s_tok[row] = cn ? ai : lab;
                } else if (blk == 0) {
                    s_ce[row] += logZ - sv;
                }
            }
        }
        __syncthreads();
    }

    if (blk == 0 && tid == 0) {
        float tot = 0.f;
        for (int r = 0; r < 32; ++r) tot += s_ce[r];
        *out = tot / 32.f;
    }
}

// ===========================================================================
// FALLBACK (R4 multi-kernel path, proven at 1736us) — used only if the
// cooperative launch is rejected by the runtime.
// ===========================================================================
#define KSPLIT 8
#define KS_LOG 2
#define FLCB 128
#define FNCB (VOCABSZ / FLCB)

__global__ void init_kernel(const float* __restrict__ x,
                            const float* __restrict__ emb,
                            const void* __restrict__ coin,
                            float* __restrict__ h, float* __restrict__ c,
                            float* __restrict__ inp,
                            float* __restrict__ ce_acc, int* __restrict__ flag) {
    int tid = threadIdx.x;
    if (tid == 0) {
        const unsigned int* cw = (const unsigned int*)coin;
        int f = 0;
        for (int i = 0; i < 256; ++i) if (cw[i] > 1u) f = 1;
        *flag = f;
    }
    if (tid < 32) ce_acc[tid] = 0.f;
    for (int i = tid; i < BSZ * HIDD; i += blockDim.x) {
        h[i] = x[i];
        c[i] = 0.f;
        inp[i] = emb[1 * EMBD + (i & (EMBD - 1))];
    }
}

__global__ __launch_bounds__(256) void cell_mm_kernel(
    const float* __restrict__ inp, const float* __restrict__ Wi,
    const float* __restrict__ Wh, const float* __restrict__ hsrc,
    float* __restrict__ pg) {
    __shared__ float s_x[128][36];
    int tid = threadIdx.x;
    int ks = blockIdx.x & 7;
    int colblk = blockIdx.x >> 3;
    int cidx = tid & 31;
    int rowg = tid >> 5;
    int j = colblk * 32 + cidx;
    const float* X = (ks < 4) ? inp : hsrc;
    const float* W = (ks < 4) ? Wi : Wh;
    int kb = (ks & 3) * 128;
    #pragma unroll
    for (int p = 0; p < 16; ++p) {
        int idx = p * 256 + tid;
        int kk = idx & 127, r = idx >> 7;
        s_x[kk][r] = X[r * HIDD + kb + kk];
    }
    __syncthreads();
    float acc[4] = {0.f, 0.f, 0.f, 0.f};
    #pragma unroll 8
    for (int kk = 0; kk < 128; ++kk) {
        float w = W[(size_t)(kb + kk) * G4 + j];
        float4 xx = *(const float4*)&s_x[kk][rowg * 4];
        acc[0] += xx.x * w; acc[1] += xx.y * w; acc[2] += xx.z * w; acc[3] += xx.w * w;
    }
    #pragma unroll
    for (int rr = 0; rr < 4; ++rr)
        pg[((size_t)ks * 32 + rowg * 4 + rr) * G4 + j] = acc[rr];
}

__global__ __launch_bounds__(256) void cell_act_kernel(
    const float* __restrict__ pg, const float* __restrict__ bias,
    float* __restrict__ c, float* __restrict__ hdst) {
    int idx = blockIdx.x * 256 + threadIdx.x;
    int r = idx >> 9;
    int j = idx & 511;
    float i_ = bias[j], f_ = bias[j + 512], g_ = bias[j + 1024], o_ = bias[j + 1536];
    #pragma unroll
    for (int s = 0; s < KSPLIT; ++s) {
        const float* p = pg + (size_t)s * 32 * G4 + (size_t)r * G4;
        i_ += p[j]; f_ += p[j + 512]; g_ += p[j + 1024]; o_ += p[j + 1536];
    }
    float ci = c[r * HIDD + j];
    float cn = sigmoidf_(f_) * ci + sigmoidf_(i_) * tanhf(g_);
    c[r * HIDD + j] = cn;
    hdst[r * HIDD + j] = sigmoidf_(o_) * tanhf(cn);
}

__global__ __launch_bounds__(256) void logits_mm_kernel(
    const float* __restrict__ h, const float* __restrict__ Wo,
    float* __restrict__ lp) {
    __shared__ float s_w[2][32][128];
    __shared__ float s_h[2][32][36];
    int tid = threadIdx.x;
    int cb = blockIdx.x >> 1;
    int ks = blockIdx.x & 1;
    int c0 = cb * FLCB;
    int kbase0 = ks * 256;
    int c4 = tid & 31;
    int rg = tid >> 5;
    int skk = tid & 31;
    int sr = tid >> 5;
    float acc[4][4];
    #pragma unroll
    for (int a = 0; a < 4; ++a)
        #pragma unroll
        for (int q = 0; q < 4; ++q) acc[a][q] = 0.f;
    {
        int kb = kbase0;
        #pragma unroll
        for (int p = 0; p < 4; ++p) {
            int kk = p * 8 + sr;
            *(float4*)&s_w[0][kk][c4 * 4] =
                *(const float4*)&Wo[(size_t)(kb + kk) * VOCABSZ + c0 + c4 * 4];
            s_h[0][skk][p * 8 + sr] = h[(p * 8 + sr) * HIDD + kb + skk];
        }
    }
    __syncthreads();
    float4 wr[4];
    float hr[4];
    for (int tt = 0; tt < 8; ++tt) {
        int cur = tt & 1;
        if (tt < 7) {
            int kb = kbase0 + (tt + 1) * 32;
            #pragma unroll
            for (int p = 0; p < 4; ++p) {
                int kk = p * 8 + sr;
                wr[p] = *(const float4*)&Wo[(size_t)(kb + kk) * VOCABSZ + c0 + c4 * 4];
                hr[p] = h[(p * 8 + sr) * HIDD + kb + skk];
            }
        }
        #pragma unroll
        for (int kk = 0; kk < 32; ++kk) {
            float4 w = *(const float4*)&s_w[cur][kk][c4 * 4];
            float4 hh = *(const float4*)&s_h[cur][kk][rg * 4];
            acc[0][0] += hh.x * w.x; acc[0][1] += hh.x * w.y;
            acc[0][2] += hh.x * w.z; acc[0][3] += hh.x * w.w;
            acc[1][0] += hh.y * w.x; acc[1][1] += hh.y * w.y;
            acc[1][2] += hh.y * w.z; acc[1][3] += hh.y * w.w;
            acc[2][0] += hh.z * w.x; acc[2][1] += hh.z * w.y;
            acc[2][2] += hh.z * w.z; acc[2][3] += hh.z * w.w;
            acc[3][0] += hh.w * w.x; acc[3][1] += hh.w * w.y;
            acc[3][2] += hh.w * w.z; acc[3][3] += hh.w * w.w;
        }
        __syncthreads();
        if (tt < 7) {
            int nb = cur ^ 1;
            #pragma unroll
            for (int p = 0; p < 4; ++p) {
                int kk = p * 8 + sr;
                *(float4*)&s_w[nb][kk][c4 * 4] = wr[p];
                s_h[nb][skk][p * 8 + sr] = hr[p];
            }
        }
        __syncthreads();
    }
    #pragma unroll
    for (int rr = 0; rr < 4; ++rr) {
        float4 v;
        v.x = acc[rr][0]; v.y = acc[rr][1]; v.z = acc[rr][2]; v.w = acc[rr][3];
        *(float4*)&lp[((size_t)ks * 32 + rg * 4 + rr) * VOCABSZ + c0 + c4 * 4] = v;
    }
}

__global__ __launch_bounds__(1024) void softmax_kernel(
    const float* __restrict__ lp, const float* __restrict__ bo,
    const int* __restrict__ labels, const void* __restrict__ coin,
    const int* __restrict__ flag, const float* __restrict__ emb,
    float* __restrict__ inp, float* __restrict__ ce_acc,
    int t, int is_final) {
    __shared__ float w_m[16], w_s[16], w_av[16], w_lab[16], w_stop[16];
    __shared__ int w_ai[16];
    __shared__ int s_tok;
    int row = blockIdx.x;
    int tid = threadIdx.x;
    int lab = labels[row * TLEN + (is_final ? 0 : t)];
    const float* lp0 = lp + (size_t)row * VOCABSZ;
    const float* lp1 = lp + (size_t)(32 + row) * VOCABSZ;
    float v[32];
    #pragma unroll
    for (int j = 0; j < 8; ++j) {
        int ch = j * 1024 + tid;
        if (ch < VOCABSZ / 4) {
            float4 a = *(const float4*)&lp0[ch * 4];
            float4 b4 = *(const float4*)&lp1[ch * 4];
            float4 bb = *(const float4*)&bo[ch * 4];
            v[j * 4 + 0] = a.x + b4.x + bb.x;
            v[j * 4 + 1] = a.y + b4.y + bb.y;
            v[j * 4 + 2] = a.z + b4.z + bb.z;
            v[j * 4 + 3] = a.w + b4.w + bb.w;
        } else {
            v[j * 4 + 0] = -INFINITY; v[j * 4 + 1] = -INFINITY;
            v[j * 4 + 2] = -INFINITY; v[j * 4 + 3] = -INFINITY;
        }
    }
    float m = -INFINITY; int mi = 0;
    float slab = -INFINITY, sstop = -INFINITY;
    #pragma unroll
    for (int i = 0; i < 32; ++i) {
        int idx = ((i >> 2) * 1024 + tid) * 4 + (i & 3);
        if (v[i] > m) { m = v[i]; mi = idx; }
        if (idx == lab) slab = v[i];
        if (idx == 2) sstop = v[i];
    }
    float s = 0.f;
    #pragma unroll
    for (int i = 0; i < 32; ++i) s += expf(v[i] - m);
    #pragma unroll
    for (int d = 1; d < 64; d <<= 1) {
        float om = __shfl_xor(m, d);
        int omi = __shfl_xor(mi, d);
        float os = __shfl_xor(s, d);
        float nM = fmaxf(m, om);
        s = s * expf(m - nM) + os * expf(om - nM);
        if (om > m || (om == m && omi < mi)) { mi = omi; }
        m = nM;
        slab = fmaxf(slab, __shfl_xor(slab, d));
        sstop = fmaxf(sstop, __shfl_xor(sstop, d));
    }
    int wv = tid >> 6;
    if ((tid & 63) == 0) {
        w_m[wv] = m; w_s[wv] = s; w_av[wv] = m; w_ai[wv] = mi;
        w_lab[wv] = slab; w_stop[wv] = sstop;
    }
    __syncthreads();
    if (tid == 0) {
        float M = -INFINITY, S = 0.f, AV = -INFINITY, LB = -INFINITY, ST = -INFINITY;
        int AI = 0;
        for (int k = 0; k < 16; ++k) {
            float pm = w_m[k], ps = w_s[k];
            float nM = fmaxf(M, pm);
            S = S * expf(M - nM) + ps * expf(pm - nM);
            M = nM;
            if (w_av[k] > AV || (w_av[k] == AV && w_ai[k] < AI)) { AV = w_av[k]; AI = w_ai[k]; }
            LB = fmaxf(LB, w_lab[k]);
            ST = fmaxf(ST, w_stop[k]);
        }
        float logZ = M + logf(S);
        float ce = logZ - (is_final ? ST : LB);
        ce_acc[row] += ce;
        if (!is_final) {
            int cn;
            if (*flag) cn = ((const unsigned char*)coin)[row * TLEN + t];
            else       cn = ((const int*)coin)[row * TLEN + t];
            s_tok = cn ? AI : lab;
        }
    }
    __syncthreads();
    if (!is_final && tid < 128) {
        *(float4*)&inp[row * EMBD + tid * 4] =
            *(const float4*)&emb[(size_t)s_tok * EMBD + tid * 4];
    }
}

__global__ void finalize_kernel(const float* __restrict__ ce_acc,
                                float* __restrict__ out) {
    if (threadIdx.x == 0) {
        float tot = 0.f;
        for (int r = 0; r < 32; ++r) tot += ce_acc[r];
        *out = tot / 32.f;
    }
}

// ===========================================================================
extern "C" void kernel_launch(void* const* d_in, const int* in_sizes, int n_in,
                              void* d_out, int out_size, void* d_ws, size_t ws_size,
                              hipStream_t stream) {
    const float* x      = (const float*)d_in[0];
    const int*   labels = (const int*)  d_in[1];
    const void*  coin   =               d_in[2];
    const float* emb    = (const float*)d_in[3];
    const float* Wi     = (const float*)d_in[4];
    const float* Wh     = (const float*)d_in[5];
    const float* b      = (const float*)d_in[6];
    const float* Wo     = (const float*)d_in[7];
    const float* bo     = (const float*)d_in[8];

    float* ws     = (float*)d_ws;
    float* hA     = ws;                    // 16384
    float* hB     = ws + 16384;            // 16384
    float* cst    = ws + 32768;            // 16384
    float* uni    = ws + 49152;            // 2048000 (fb: pg then lp; mega: unused)
    float* part   = ws + 2097152;          // 5*8192 = 40960 (mega)
    float* ce_acc = ws + 2138112;          // 32 (fb)
    int*   flag   = (int*)(ws + 2138144);  // 1 (fb)
    float* inp    = ws + 2138148;          // 16384 (fb)
    float* outp   = (float*)d_out;

    void* args[] = {
        (void*)&x, (void*)&labels, (void*)&coin, (void*)&emb,
        (void*)&Wi, (void*)&Wh, (void*)&b, (void*)&Wo, (void*)&bo,
        (void*)&hA, (void*)&hB, (void*)&cst, (void*)&part, (void*)&outp
    };
    hipError_t err = hipLaunchCooperativeKernel((void*)mega3_kernel, dim3(NB),
                                                dim3(512), args, 0, stream);
    if (err != hipSuccess) {
        (void)hipGetLastError();   // clear sticky error; deterministic fallback
        float* pg = uni;           // 8*32*2048 = 524288 (dead after cell_act)
        float* lp = uni;           // 2*32*32000 = 2048000 (live logits->softmax)
        init_kernel<<<1, 256, 0, stream>>>(x, emb, coin, hA, cst, inp, ce_acc, flag);
        float* hsrc = hA;
        float* hdst = hB;
        for (int t = 0; t < 33; ++t) {
            cell_mm_kernel<<<512, 256, 0, stream>>>(inp, Wi, Wh, hsrc, pg);
            cell_act_kernel<<<64, 256, 0, stream>>>(pg, b, cst, hdst);
            logits_mm_kernel<<<FNCB * KS_LOG, 256, 0, stream>>>(hdst, Wo, lp);
            softmax_kernel<<<32, 1024, 0, stream>>>(lp, bo, labels, coin, flag,
                                                    emb, inp, ce_acc, t,
                                                    t == 32 ? 1 : 0);
            float* tmp = hsrc; hsrc = hdst; hdst = tmp;
        }
        finalize_kernel<<<1, 64, 0, stream>>>(ce_acc, outp);
    }
}

// Round 8
// 1221.938 us; speedup vs baseline: 4.8931x; 4.5955x over previous
//
#include <hip/hip_runtime.h>
#include <math.h>

#define VOCABSZ 32000
#define EMBD 512
#define HIDD 512
#define BSZ 32
#define TLEN 32
#define G4 2048
#define KSPLIT 8
#define NGRP 1000            // vocab col-groups of 32
#define PSTRIDE 8192         // part array stride (32 rows * 256 slots)

using bf16x8 = __attribute__((ext_vector_type(8))) short;
using f32x16 = __attribute__((ext_vector_type(16))) float;

__device__ __forceinline__ float sigmoidf_(float x) { return 1.f / (1.f + expf(-x)); }
__device__ __forceinline__ unsigned short f2bf(float f) {
    unsigned u = __float_as_uint(f);
    unsigned r = (u + 0x7fffu + ((u >> 16) & 1u)) >> 16;   // RNE
    return (unsigned short)r;
}

// ---------------------------------------------------------------------------
// init: h <- x, c <- 0, inp <- emb[START], ce_acc <- 0, coin dtype probe
// ---------------------------------------------------------------------------
__global__ void init_kernel(const float* __restrict__ x,
                            const float* __restrict__ emb,
                            const void* __restrict__ coin,
                            float* __restrict__ h, float* __restrict__ c,
                            float* __restrict__ inp,
                            float* __restrict__ ce_acc, int* __restrict__ flag) {
    int tid = threadIdx.x;
    if (tid == 0) {
        const unsigned int* cw = (const unsigned int*)coin;
        int f = 0;
        for (int i = 0; i < 256; ++i) if (cw[i] > 1u) f = 1;
        *flag = f;
    }
    if (tid < 32) ce_acc[tid] = 0.f;
    for (int i = tid; i < BSZ * HIDD; i += blockDim.x) {
        h[i] = x[i];
        c[i] = 0.f;
        inp[i] = emb[1 * EMBD + (i & (EMBD - 1))];   // START = 1
    }
}

// ---------------------------------------------------------------------------
// wot_prep: Wo [512][32000] fp32 -> bf16 in MFMA B-fragment order:
//   wot8[(g*32 + kt)*64 + lane] = { Wo[kt*16 + (lane>>5)*8 + j][g*32 + (lane&31)] }
// One block per col-group g (32 cols), staged via LDS.
// ---------------------------------------------------------------------------
__global__ __launch_bounds__(256) void wot_prep_kernel(
    const float* __restrict__ Wo, unsigned short* __restrict__ wot) {
    __shared__ unsigned short s[512 * 32];     // [k][col] 32 KB
    int g = blockIdx.x;
    int tid = threadIdx.x;
    int col = tid & 31;
    int k0 = tid >> 5;
    for (int kk = k0; kk < 512; kk += 8)
        s[kk * 32 + col] = f2bf(Wo[(size_t)kk * VOCABSZ + g * 32 + col]);
    __syncthreads();
    bf16x8* out8 = (bf16x8*)wot;
    for (int f = tid; f < 2048; f += 256) {
        int kt = f >> 6, lane = f & 63;
        int kb = kt * 16 + ((lane >> 5) << 3);
        int c = lane & 31;
        bf16x8 v;
        #pragma unroll
        for (int j = 0; j < 8; ++j) v[j] = (short)s[(kb + j) * 32 + c];
        out8[(size_t)g * 2048 + f] = v;
    }
}

// ---------------------------------------------------------------------------
// cell_mm: partial gates (fp32 exact). 512 blocks = 64 colblk x 8 ksplit.
// ---------------------------------------------------------------------------
__global__ __launch_bounds__(256) void cell_mm_kernel(
    const float* __restrict__ inp, const float* __restrict__ Wi,
    const float* __restrict__ Wh, const float* __restrict__ hsrc,
    float* __restrict__ pg) {
    __shared__ float s_x[128][36];
    int tid = threadIdx.x;
    int ks = blockIdx.x & 7;
    int colblk = blockIdx.x >> 3;
    int cidx = tid & 31;
    int rowg = tid >> 5;
    int j = colblk * 32 + cidx;
    const float* X = (ks < 4) ? inp : hsrc;
    const float* W = (ks < 4) ? Wi : Wh;
    int kb = (ks & 3) * 128;
    #pragma unroll
    for (int p = 0; p < 16; ++p) {
        int idx = p * 256 + tid;
        int kk = idx & 127, r = idx >> 7;
        s_x[kk][r] = X[r * HIDD + kb + kk];
    }
    __syncthreads();
    float acc[4] = {0.f, 0.f, 0.f, 0.f};
    #pragma unroll 8
    for (int kk = 0; kk < 128; ++kk) {
        float w = W[(size_t)(kb + kk) * G4 + j];
        float4 xx = *(const float4*)&s_x[kk][rowg * 4];
        acc[0] += xx.x * w; acc[1] += xx.y * w; acc[2] += xx.z * w; acc[3] += xx.w * w;
    }
    #pragma unroll
    for (int rr = 0; rr < 4; ++rr)
        pg[((size_t)ks * 32 + rowg * 4 + rr) * G4 + j] = acc[rr];
}

// ---------------------------------------------------------------------------
// cell_act: sum partials + bias, gate math, update c; write h (fp32 + bf16)
// ---------------------------------------------------------------------------
__global__ __launch_bounds__(256) void cell_act_kernel(
    const float* __restrict__ pg, const float* __restrict__ bias,
    float* __restrict__ c, float* __restrict__ hdst,
    unsigned short* __restrict__ hbf) {
    int idx = blockIdx.x * 256 + threadIdx.x;
    int r = idx >> 9;
    int j = idx & 511;
    float i_ = bias[j], f_ = bias[j + 512], g_ = bias[j + 1024], o_ = bias[j + 1536];
    #pragma unroll
    for (int s = 0; s < KSPLIT; ++s) {
        const float* p = pg + (size_t)s * 32 * G4 + (size_t)r * G4;
        i_ += p[j]; f_ += p[j + 512]; g_ += p[j + 1024]; o_ += p[j + 1536];
    }
    float ci = c[idx];
    float cn = sigmoidf_(f_) * ci + sigmoidf_(i_) * tanhf(g_);
    float hn = sigmoidf_(o_) * tanhf(cn);
    c[idx] = cn;
    hdst[idx] = hn;
    hbf[idx] = f2bf(hn);
}

// ---------------------------------------------------------------------------
// logits_mfma: 250 blocks x 256 thr (4 waves). Wave = 32 vocab cols, K=512
// via 32x mfma_f32_32x32x16_bf16. h_bf staged in LDS in A-fragment order
// (linear ds_read_b128). Wo read from pre-swizzled wot8 (coalesced 1KB wave
// loads). Epilogue: per-row softmax partials (max/sumexp/argmax/label/STOP),
// block-combined -> part SoA [5][32][256-stride], entry = blockIdx.
// C/D layout: col = lane&31, row = (reg&3) + 8*(reg>>2) + 4*(lane>>5).
// ---------------------------------------------------------------------------
__global__ __launch_bounds__(256) void logits_mfma_kernel(
    const unsigned short* __restrict__ wot, const unsigned short* __restrict__ h_bf,
    const float* __restrict__ bo, const int* __restrict__ labels,
    float* __restrict__ part, int t) {
    __shared__ __align__(16) unsigned short s_h[16384];   // 32 KB frag-order
    __shared__ int s_lab[32];
    __shared__ float s_pm[4][32], s_ps[4][32], s_pl[4][32], s_pst[4][32];
    __shared__ int s_pi[4][32];
    int tid = threadIdx.x;
    int lane = tid & 63, wv = tid >> 6;

    for (int f = tid; f < 2048; f += 256) {
        int kt = f >> 6, ln = f & 63;
        int row = ln & 31, kb = kt * 16 + ((ln >> 5) << 3);
        *(bf16x8*)&s_h[f * 8] = *(const bf16x8*)&h_bf[row * 512 + kb];
    }
    if (tid < 32) s_lab[tid] = labels[tid * TLEN + t];
    __syncthreads();

    int g = blockIdx.x * 4 + wv;                 // col-group 0..999
    const bf16x8* wp = (const bf16x8*)wot + (size_t)g * 2048 + lane;
    const bf16x8* sh8 = (const bf16x8*)s_h;

    f32x16 acc = {};
    #pragma unroll 8
    for (int kt = 0; kt < 32; ++kt) {
        bf16x8 a = sh8[kt * 64 + lane];
        bf16x8 b = wp[kt * 64];
        acc = __builtin_amdgcn_mfma_f32_32x32x16_bf16(a, b, acc, 0, 0, 0);
    }

    int half = lane >> 5;
    int colw = lane & 31;
    int col = g * 32 + colw;
    float bq = bo[col];

    #pragma unroll
    for (int reg = 0; reg < 16; ++reg) {
        int row = (reg & 3) + 8 * (reg >> 2) + 4 * half;
        float v = acc[reg] + bq;
        float m = v; int mi = col;
        #pragma unroll
        for (int d = 1; d < 32; d <<= 1) {
            float om = __shfl_xor(m, d);
            int omi = __shfl_xor(mi, d);
            if (om > m || (om == m && omi < mi)) { m = om; mi = omi; }
        }
        float e = expf(v - m), ssum = e;
        #pragma unroll
        for (int d = 1; d < 32; d <<= 1) ssum += __shfl_xor(ssum, d);
        int labc = s_lab[row];
        float lv = __shfl(v, (labc & 31) + (half << 5));
        if ((labc >> 5) != g) lv = -INFINITY;
        float sv = __shfl(v, 2 + (half << 5));   // STOP = 2
        if (g != 0) sv = -INFINITY;
        if (colw == 0) {
            s_pm[wv][row] = m; s_ps[wv][row] = ssum; s_pi[wv][row] = mi;
            s_pl[wv][row] = lv; s_pst[wv][row] = sv;
        }
    }
    __syncthreads();

    if (tid < 32) {
        int row = tid;
        float M = s_pm[0][row], S = s_ps[0][row];
        int MI = s_pi[0][row];
        float L = s_pl[0][row], ST = s_pst[0][row];
        #pragma unroll
        for (int w = 1; w < 4; ++w) {
            float pm = s_pm[w][row], ps = s_ps[w][row];
            int pi = s_pi[w][row];
            float nM = fmaxf(M, pm);
            float nS = S * expf(M - nM) + ps * expf(pm - nM);
            if (pm > M || (pm == M && pi < MI)) MI = pi;
            M = nM; S = nS;
            L = fmaxf(L, s_pl[w][row]);
            ST = fmaxf(ST, s_pst[w][row]);
        }
        int e0 = row * 256 + blockIdx.x;
        part[e0] = M;
        part[PSTRIDE + e0] = S;
        part[2 * PSTRIDE + e0] = __int_as_float(MI);
        part[3 * PSTRIDE + e0] = L;
        part[4 * PSTRIDE + e0] = ST;
    }
}

// ---------------------------------------------------------------------------
// reduce2: 32 blocks (1/row) x 256 thr. Combine 250 block-partials; CE
// accumulate; token select; emb gather -> inp.
// ---------------------------------------------------------------------------
__global__ __launch_bounds__(256) void reduce2_kernel(
    const float* __restrict__ part, const int* __restrict__ labels,
    const void* __restrict__ coin, const int* __restrict__ flag,
    const float* __restrict__ emb, float* __restrict__ inp,
    float* __restrict__ ce_acc, int t, int is_final) {
    __shared__ float r_m[4], r_s[4], r_l[4], r_st[4];
    __shared__ int r_i[4];
    __shared__ int s_tok;
    int row = blockIdx.x, tid = threadIdx.x, lane = tid & 63, wv = tid >> 6;

    // -3e38 (not -inf) so inactive-lane merges never produce 0*exp(nan)=nan
    float M = -3.0e38f, S = 0.f, L = -INFINITY, ST = -INFINITY;
    int MI = 0;
    if (tid < 250) {
        int e = row * 256 + tid;
        M = part[e];
        S = part[PSTRIDE + e];
        MI = __float_as_int(part[2 * PSTRIDE + e]);
        L = part[3 * PSTRIDE + e];
        ST = part[4 * PSTRIDE + e];
    }
    #pragma unroll
    for (int d = 1; d < 64; d <<= 1) {
        float oM = __shfl_xor(M, d), oS = __shfl_xor(S, d);
        int oI = __shfl_xor(MI, d);
        float oL = __shfl_xor(L, d), oST = __shfl_xor(ST, d);
        float nM = fmaxf(M, oM);
        S = S * expf(M - nM) + oS * expf(oM - nM);
        if (oM > M || (oM == M && oI < MI)) MI = oI;
        M = nM;
        L = fmaxf(L, oL);
        ST = fmaxf(ST, oST);
    }
    if (lane == 0) { r_m[wv] = M; r_s[wv] = S; r_i[wv] = MI; r_l[wv] = L; r_st[wv] = ST; }
    __syncthreads();
    if (tid == 0) {
        float FM = r_m[0], FS = r_s[0], FL = r_l[0], FST = r_st[0];
        int FI = r_i[0];
        #pragma unroll
        for (int w = 1; w < 4; ++w) {
            float pm = r_m[w], ps = r_s[w];
            float nM = fmaxf(FM, pm);
            FS = FS * expf(FM - nM) + ps * expf(pm - nM);
            if (pm > FM || (pm == FM && r_i[w] < FI)) FI = r_i[w];
            FM = nM;
            FL = fmaxf(FL, r_l[w]);
            FST = fmaxf(FST, r_st[w]);
        }
        float logZ = FM + logf(FS);
        float ce = logZ - (is_final ? FST : FL);
        ce_acc[row] += ce;
        if (!is_final) {
            int lab = labels[row * TLEN + t];
            int cn = (*flag) ? (int)((const unsigned char*)coin)[row * TLEN + t]
                             : ((const int*)coin)[row * TLEN + t];
            s_tok = cn ? FI : lab;
        }
    }
    __syncthreads();
    if (!is_final && tid < 128) {
        *(float4*)&inp[row * EMBD + tid * 4] =
            *(const float4*)&emb[(size_t)s_tok * EMBD + tid * 4];
    }
}

__global__ void finalize_kernel(const float* __restrict__ ce_acc,
                                float* __restrict__ out) {
    if (threadIdx.x == 0) {
        float tot = 0.f;
        for (int r = 0; r < 32; ++r) tot += ce_acc[r];
        *out = tot / 32.f;
    }
}

// ===========================================================================
// FALLBACK fp32 logits path (R4, proven) — used only if ws_size < 35.3 MB.
// ===========================================================================
#define KS_LOG 2
#define FLCB 128
#define FNCB (VOCABSZ / FLCB)

__global__ __launch_bounds__(256) void logits_mm_kernel(
    const float* __restrict__ h, const float* __restrict__ Wo,
    float* __restrict__ lp) {
    __shared__ float s_w[2][32][128];
    __shared__ float s_h[2][32][36];
    int tid = threadIdx.x;
    int cb = blockIdx.x >> 1;
    int ks = blockIdx.x & 1;
    int c0 = cb * FLCB;
    int kbase0 = ks * 256;
    int c4 = tid & 31;
    int rg = tid >> 5;
    int skk = tid & 31;
    int sr = tid >> 5;
    float acc[4][4];
    #pragma unroll
    for (int a = 0; a < 4; ++a)
        #pragma unroll
        for (int q = 0; q < 4; ++q) acc[a][q] = 0.f;
    {
        #pragma unroll
        for (int p = 0; p < 4; ++p) {
            int kk = p * 8 + sr;
            *(float4*)&s_w[0][kk][c4 * 4] =
                *(const float4*)&Wo[(size_t)(kbase0 + kk) * VOCABSZ + c0 + c4 * 4];
            s_h[0][skk][p * 8 + sr] = h[(p * 8 + sr) * HIDD + kbase0 + skk];
        }
    }
    __syncthreads();
    float4 wr[4];
    float hr[4];
    for (int tt = 0; tt < 8; ++tt) {
        int cur = tt & 1;
        if (tt < 7) {
            int kb = kbase0 + (tt + 1) * 32;
            #pragma unroll
            for (int p = 0; p < 4; ++p) {
                int kk = p * 8 + sr;
                wr[p] = *(const float4*)&Wo[(size_t)(kb + kk) * VOCABSZ + c0 + c4 * 4];
                hr[p] = h[(p * 8 + sr) * HIDD + kb + skk];
            }
        }
        #pragma unroll
        for (int kk = 0; kk < 32; ++kk) {
            float4 w = *(const float4*)&s_w[cur][kk][c4 * 4];
            float4 hh = *(const float4*)&s_h[cur][kk][rg * 4];
            acc[0][0] += hh.x * w.x; acc[0][1] += hh.x * w.y;
            acc[0][2] += hh.x * w.z; acc[0][3] += hh.x * w.w;
            acc[1][0] += hh.y * w.x; acc[1][1] += hh.y * w.y;
            acc[1][2] += hh.y * w.z; acc[1][3] += hh.y * w.w;
            acc[2][0] += hh.z * w.x; acc[2][1] += hh.z * w.y;
            acc[2][2] += hh.z * w.z; acc[2][3] += hh.z * w.w;
            acc[3][0] += hh.w * w.x; acc[3][1] += hh.w * w.y;
            acc[3][2] += hh.w * w.z; acc[3][3] += hh.w * w.w;
        }
        __syncthreads();
        if (tt < 7) {
            int nb = cur ^ 1;
            #pragma unroll
            for (int p = 0; p < 4; ++p) {
                int kk = p * 8 + sr;
                *(float4*)&s_w[nb][kk][c4 * 4] = wr[p];
                s_h[nb][skk][p * 8 + sr] = hr[p];
            }
        }
        __syncthreads();
    }
    #pragma unroll
    for (int rr = 0; rr < 4; ++rr) {
        float4 v;
        v.x = acc[rr][0]; v.y = acc[rr][1]; v.z = acc[rr][2]; v.w = acc[rr][3];
        *(float4*)&lp[((size_t)ks * 32 + rg * 4 + rr) * VOCABSZ + c0 + c4 * 4] = v;
    }
}

__global__ __launch_bounds__(1024) void softmax_kernel(
    const float* __restrict__ lp, const float* __restrict__ bo,
    const int* __restrict__ labels, const void* __restrict__ coin,
    const int* __restrict__ flag, const float* __restrict__ emb,
    float* __restrict__ inp, float* __restrict__ ce_acc,
    int t, int is_final) {
    __shared__ float w_m[16], w_s[16], w_av[16], w_lab[16], w_stop[16];
    __shared__ int w_ai[16];
    __shared__ int s_tok;
    int row = blockIdx.x;
    int tid = threadIdx.x;
    int lab = labels[row * TLEN + (is_final ? 0 : t)];
    const float* lp0 = lp + (size_t)row * VOCABSZ;
    const float* lp1 = lp + (size_t)(32 + row) * VOCABSZ;
    float v[32];
    #pragma unroll
    for (int j = 0; j < 8; ++j) {
        int ch = j * 1024 + tid;
        if (ch < VOCABSZ / 4) {
            float4 a = *(const float4*)&lp0[ch * 4];
            float4 b4 = *(const float4*)&lp1[ch * 4];
            float4 bb = *(const float4*)&bo[ch * 4];
            v[j * 4 + 0] = a.x + b4.x + bb.x;
            v[j * 4 + 1] = a.y + b4.y + bb.y;
            v[j * 4 + 2] = a.z + b4.z + bb.z;
            v[j * 4 + 3] = a.w + b4.w + bb.w;
        } else {
            v[j * 4 + 0] = -INFINITY; v[j * 4 + 1] = -INFINITY;
            v[j * 4 + 2] = -INFINITY; v[j * 4 + 3] = -INFINITY;
        }
    }
    float m = -INFINITY; int mi = 0;
    float slab = -INFINITY, sstop = -INFINITY;
    #pragma unroll
    for (int i = 0; i < 32; ++i) {
        int idx = ((i >> 2) * 1024 + tid) * 4 + (i & 3);
        if (v[i] > m) { m = v[i]; mi = idx; }
        if (idx == lab) slab = v[i];
        if (idx == 2) sstop = v[i];
    }
    float s = 0.f;
    #pragma unroll
    for (int i = 0; i < 32; ++i) s += expf(v[i] - m);
    #pragma unroll
    for (int d = 1; d < 64; d <<= 1) {
        float om = __shfl_xor(m, d);
        int omi = __shfl_xor(mi, d);
        float os = __shfl_xor(s, d);
        float nM = fmaxf(m, om);
        s = s * expf(m - nM) + os * expf(om - nM);
        if (om > m || (om == m && omi < mi)) { mi = omi; }
        m = nM;
        slab = fmaxf(slab, __shfl_xor(slab, d));
        sstop = fmaxf(sstop, __shfl_xor(sstop, d));
    }
    int wv = tid >> 6;
    if ((tid & 63) == 0) {
        w_m[wv] = m; w_s[wv] = s; w_av[wv] = m; w_ai[wv] = mi;
        w_lab[wv] = slab; w_stop[wv] = sstop;
    }
    __syncthreads();
    if (tid == 0) {
        float M = -INFINITY, S = 0.f, AV = -INFINITY, LB = -INFINITY, ST = -INFINITY;
        int AI = 0;
        for (int k = 0; k < 16; ++k) {
            float pm = w_m[k], ps = w_s[k];
            float nM = fmaxf(M, pm);
            S = S * expf(M - nM) + ps * expf(pm - nM);
            M = nM;
            if (w_av[k] > AV || (w_av[k] == AV && w_ai[k] < AI)) { AV = w_av[k]; AI = w_ai[k]; }
            LB = fmaxf(LB, w_lab[k]);
            ST = fmaxf(ST, w_stop[k]);
        }
        float logZ = M + logf(S);
        float ce = logZ - (is_final ? ST : LB);
        ce_acc[row] += ce;
        if (!is_final) {
            int cn;
            if (*flag) cn = ((const unsigned char*)coin)[row * TLEN + t];
            else       cn = ((const int*)coin)[row * TLEN + t];
            s_tok = cn ? AI : lab;
        }
    }
    __syncthreads();
    if (!is_final && tid < 128) {
        *(float4*)&inp[row * EMBD + tid * 4] =
            *(const float4*)&emb[(size_t)s_tok * EMBD + tid * 4];
    }
}

// ===========================================================================
extern "C" void kernel_launch(void* const* d_in, const int* in_sizes, int n_in,
                              void* d_out, int out_size, void* d_ws, size_t ws_size,
                              hipStream_t stream) {
    const float* x      = (const float*)d_in[0];
    const int*   labels = (const int*)  d_in[1];
    const void*  coin   =               d_in[2];
    const float* emb    = (const float*)d_in[3];
    const float* Wi     = (const float*)d_in[4];
    const float* Wh     = (const float*)d_in[5];
    const float* b      = (const float*)d_in[6];
    const float* Wo     = (const float*)d_in[7];
    const float* bo     = (const float*)d_in[8];

    float* ws     = (float*)d_ws;
    float* hA     = ws;                      // 16384
    float* hB     = ws + 16384;              // 16384
    float* cst    = ws + 32768;              // 16384
    float* inp    = ws + 49152;              // 16384
    float* pg     = ws + 65536;              // 524288
    float* part   = ws + 589824;             // 40960
    float* ce_acc = ws + 630784;             // 32
    int*   flag   = (int*)(ws + 630816);     // 1
    unsigned short* h_bf = (unsigned short*)(ws + 630820);   // 4096 floats
    unsigned short* wot  = (unsigned short*)(ws + 634916);   // 8192000 floats
    float* outp   = (float*)d_out;

    size_t need = (size_t)(634916 + 8192000) * 4;

    if (ws_size >= need) {
        // ---------------- bf16-MFMA path ----------------
        wot_prep_kernel<<<NGRP, 256, 0, stream>>>(Wo, wot);
        init_kernel<<<1, 256, 0, stream>>>(x, emb, coin, hA, cst, inp, ce_acc, flag);
        float* hsrc = hA;
        float* hdst = hB;
        for (int t = 0; t < 33; ++t) {
            int tt = (t < 32) ? t : 0;
            cell_mm_kernel<<<512, 256, 0, stream>>>(inp, Wi, Wh, hsrc, pg);
            cell_act_kernel<<<64, 256, 0, stream>>>(pg, b, cst, hdst, h_bf);
            logits_mfma_kernel<<<250, 256, 0, stream>>>(wot, h_bf, bo, labels, part, tt);
            reduce2_kernel<<<32, 256, 0, stream>>>(part, labels, coin, flag, emb,
                                                   inp, ce_acc, tt, t == 32 ? 1 : 0);
            float* tmp = hsrc; hsrc = hdst; hdst = tmp;
        }
        finalize_kernel<<<1, 64, 0, stream>>>(ce_acc, outp);
    } else {
        // ---------------- fp32 fallback (R4 path) ----------------
        float* lp = pg;   // needs 2048000 floats; fallback layout:
        // reuse: pg region + beyond (R4 proved >=10.5MB ws). lp at 65536.
        float* f_part  = ws + 2113536;       // after lp (65536+2048000)
        float* f_ce    = ws + 2113536 + 40960;
        int*   f_flag  = (int*)(f_ce + 32);
        unsigned short* f_hbf = (unsigned short*)(f_ce + 40);  // scratch (unused)
        init_kernel<<<1, 256, 0, stream>>>(x, emb, coin, hA, cst, inp, f_ce, f_flag);
        float* hsrc = hA;
        float* hdst = hB;
        for (int t = 0; t < 33; ++t) {
            cell_mm_kernel<<<512, 256, 0, stream>>>(inp, Wi, Wh, hsrc, pg);
            cell_act_kernel<<<64, 256, 0, stream>>>(pg, b, cst, hdst, f_hbf);
            logits_mm_kernel<<<FNCB * KS_LOG, 256, 0, stream>>>(hdst, Wo, lp);
            softmax_kernel<<<32, 1024, 0, stream>>>(lp, bo, labels, coin, f_flag,
                                                    emb, inp, f_ce, t,
                                                    t == 32 ? 1 : 0);
            float* tmp = hsrc; hsrc = hdst; hdst = tmp;
        }
        finalize_kernel<<<1, 64, 0, stream>>>(f_ce, outp);
        (void)f_part;
    }
}